// Round 3
// baseline (575.631 us; speedup 1.0000x reference)
//
#include <hip/hip_runtime.h>

#define Bn 4
#define Tn 8192
#define Dn 512
#define Cn 64
#define NCn 128
#define ALPHAc 0.03f

typedef unsigned short u16;
typedef short bf8_t __attribute__((ext_vector_type(8)));
typedef float f4_t  __attribute__((ext_vector_type(4)));
typedef u16 us8_t __attribute__((ext_vector_type(8)));
typedef u16 us4_t __attribute__((ext_vector_type(4)));

#define MFMA16(a,b,c) __builtin_amdgcn_mfma_f32_16x16x32_bf16((a),(b),(c),0,0,0)

__device__ __forceinline__ u16 f2bf(float f) {
  union { float f; unsigned u; } v; v.f = f;
  unsigned r = v.u + 0x7fffu + ((v.u >> 16) & 1u);
  return (u16)(r >> 16);
}
__device__ __forceinline__ float bf2f(u16 h) {
  union { unsigned u; float f; } v; v.u = ((unsigned)h) << 16;
  return v.f;
}

// ---------------- fp32 -> bf16 convert ----------------
__global__ __launch_bounds__(256) void k_convert(const float* __restrict__ src,
                                                 u16* __restrict__ dst, int n4) {
  int i = blockIdx.x * 256 + threadIdx.x;
  if (i >= n4) return;
  float4 v = ((const float4*)src)[i];
  us4_t o = { f2bf(v.x), f2bf(v.y), f2bf(v.z), f2bf(v.w) };
  ((us4_t*)dst)[i] = o;
}

// ---------------- K1: v = out @ w_write^T (bf16 out) ----------------
__global__ __launch_bounds__(256) void k_gemm_v(const u16* __restrict__ A,
                                                const u16* __restrict__ Bm,
                                                u16* __restrict__ Cout) {
  __shared__ u16 lds[128*72*2];
  u16* As = lds;
  u16* Bs = lds + 128*72;
  const int tid = threadIdx.x;
  const int lane = tid & 63, w = tid >> 6;
  const int g = lane >> 4, lr = lane & 15;
  const int m0 = blockIdx.y * 128, n0 = blockIdx.x * 128;
  const int wm = (w >> 1) * 64, wn = (w & 1) * 64;
  f4_t acc[4][4];
#pragma unroll
  for (int i = 0; i < 4; ++i)
#pragma unroll
    for (int j = 0; j < 4; ++j) acc[i][j] = (f4_t){0.f, 0.f, 0.f, 0.f};

  for (int kb = 0; kb < 8; ++kb) {
    const int k0 = kb * 64;
    __syncthreads();
#pragma unroll
    for (int i = 0; i < 8; ++i) {
      int slot = i * 256 + tid;
      int r = slot >> 4, c4 = (slot & 15) << 2;
      *(us4_t*)&As[r*72 + c4] = *(const us4_t*)&A[(m0 + r)*Dn + k0 + c4];
      *(us4_t*)&Bs[r*72 + c4] = *(const us4_t*)&Bm[(n0 + r)*Dn + k0 + c4];
    }
    __syncthreads();
#pragma unroll
    for (int kk = 0; kk < 2; ++kk) {
      const int co = kk*32 + g*8;
      bf8_t a[4], b[4];
#pragma unroll
      for (int mf = 0; mf < 4; ++mf) a[mf] = *(const bf8_t*)&As[(wm + mf*16 + lr)*72 + co];
#pragma unroll
      for (int nf = 0; nf < 4; ++nf) b[nf] = *(const bf8_t*)&Bs[(wn + nf*16 + lr)*72 + co];
#pragma unroll
      for (int mf = 0; mf < 4; ++mf)
#pragma unroll
        for (int nf = 0; nf < 4; ++nf)
          acc[mf][nf] = MFMA16(a[mf], b[nf], acc[mf][nf]);
    }
  }
  __syncthreads();
  u16* Cs = lds;  // [128][136]
#pragma unroll
  for (int mf = 0; mf < 4; ++mf)
#pragma unroll
    for (int nf = 0; nf < 4; ++nf)
#pragma unroll
      for (int r = 0; r < 4; ++r)
        Cs[(wm + mf*16 + g*4 + r)*136 + wn + nf*16 + lr] = f2bf(acc[mf][nf][r]);
  __syncthreads();
#pragma unroll
  for (int i = 0; i < 8; ++i) {
    int slot = i * 256 + tid;
    int r = slot >> 4, c8 = (slot & 15) << 3;
    *(us8_t*)&Cout[(m0 + r)*Dn + n0 + c8] = *(const us8_t*)&Cs[r*136 + c8];
  }
}

// ---------------- K2: sequential chunk scan over a SEGMENT of chunks ----------------
// grid (8 dj, 8 ei, 4 b); acc = running W^T tile: rows=e (M), cols=d (N)
// Stores pre-update W (bf16) per chunk slot into W_seg; fp32 state checkpointed.
__global__ __launch_bounds__(256) void k_scan(const u16* __restrict__ out_bf,
                                              const u16* __restrict__ v_bf,
                                              u16* __restrict__ W_seg,
                                              float* __restrict__ ckpt,
                                              const float* __restrict__ decay,
                                              int c0, int nc, int nslots, int initzero) {
  __shared__ u16 WkT[64*72];  // [e][t]
  __shared__ u16 VT[64*72];   // [d][t], pre-scaled by gw[t]
  const int tid = threadIdx.x;
  const int lane = tid & 63, w = tid >> 6;
  const int g = lane >> 4, lr = lane & 15;
  const int d0 = blockIdx.x * 64, e0 = blockIdx.y * 64;
  const int b = blockIdx.z;
  const int wm = (w >> 1) * 32, wn = (w & 1) * 32;
  const float gamma = 1.f / (1.f + __builtin_expf(-decay[0]));
  const float l2g = __builtin_log2f(gamma);
  const float gC = __builtin_exp2f(l2g * (float)Cn);
  const size_t bT = (size_t)b * Tn;
  f4_t acc[2][2];
#pragma unroll
  for (int mf = 0; mf < 2; ++mf)
#pragma unroll
    for (int nf = 0; nf < 2; ++nf) {
      if (initzero) {
        acc[mf][nf] = (f4_t){0.f, 0.f, 0.f, 0.f};
      } else {
        int d_g = d0 + wn + nf*16 + lr;
        int e_b = e0 + wm + mf*16 + g*4;
#pragma unroll
        for (int r = 0; r < 4; ++r)
          acc[mf][nf][r] = ckpt[((size_t)b*Dn + e_b + r)*Dn + d_g];
      }
    }

  for (int cc = 0; cc < nc; ++cc) {
    const int c = c0 + cc;
    __syncthreads();
#pragma unroll
    for (int i = 0; i < 4; ++i) {
      int slot = i * 256 + tid;
      int t = slot >> 4, q4 = (slot & 15) << 2;
      us4_t wv = {0, 0, 0, 0};
      int wr = c*Cn + t - 1;
      if (wr >= 0) wv = *(const us4_t*)&out_bf[(bT + wr)*Dn + e0 + q4];
      WkT[(q4+0)*72 + t] = wv.x;
      WkT[(q4+1)*72 + t] = wv.y;
      WkT[(q4+2)*72 + t] = wv.z;
      WkT[(q4+3)*72 + t] = wv.w;
      us4_t vv = *(const us4_t*)&v_bf[(bT + c*Cn + t)*Dn + d0 + q4];
      float gw = __builtin_exp2f(l2g * (float)(Cn - 1 - t));
      VT[(q4+0)*72 + t] = f2bf(bf2f(vv.x) * gw);
      VT[(q4+1)*72 + t] = f2bf(bf2f(vv.y) * gw);
      VT[(q4+2)*72 + t] = f2bf(bf2f(vv.z) * gw);
      VT[(q4+3)*72 + t] = f2bf(bf2f(vv.w) * gw);
    }
    // store pre-update W state (bf16), then decay accumulators
#pragma unroll
    for (int mf = 0; mf < 2; ++mf)
#pragma unroll
      for (int nf = 0; nf < 2; ++nf) {
        int e_g = e0 + wm + mf*16 + g*4;
        int d_g = d0 + wn + nf*16 + lr;
        us4_t pk = { f2bf(acc[mf][nf][0]), f2bf(acc[mf][nf][1]),
                     f2bf(acc[mf][nf][2]), f2bf(acc[mf][nf][3]) };
        *(us4_t*)&W_seg[(((size_t)b*nslots + cc)*Dn + d_g)*Dn + e_g] = pk;
        acc[mf][nf] = acc[mf][nf] * gC;
      }
    __syncthreads();
#pragma unroll
    for (int kk = 0; kk < 2; ++kk) {
      const int co = kk*32 + g*8;
      bf8_t a0 = *(const bf8_t*)&WkT[(wm + lr)*72 + co];
      bf8_t a1 = *(const bf8_t*)&WkT[(wm + 16 + lr)*72 + co];
      bf8_t b0 = *(const bf8_t*)&VT[(wn + lr)*72 + co];
      bf8_t b1 = *(const bf8_t*)&VT[(wn + 16 + lr)*72 + co];
      acc[0][0] = MFMA16(a0, b0, acc[0][0]);
      acc[0][1] = MFMA16(a0, b1, acc[0][1]);
      acc[1][0] = MFMA16(a1, b0, acc[1][0]);
      acc[1][1] = MFMA16(a1, b1, acc[1][1]);
    }
  }
  // checkpoint fp32 state for the next segment
#pragma unroll
  for (int mf = 0; mf < 2; ++mf)
#pragma unroll
    for (int nf = 0; nf < 2; ++nf) {
      int d_g = d0 + wn + nf*16 + lr;
      int e_b = e0 + wm + mf*16 + g*4;
#pragma unroll
      for (int r = 0; r < 4; ++r)
        ckpt[((size_t)b*Dn + e_b + r)*Dn + d_g] = acc[mf][nf][r];
    }
}

// ---------------- K4: reads = g_p*(rk@W^T) + (S.M)@v  (output-transposed) ----------------
// grid (2 dh, nc, 4 b); static LDS 149504 B
__global__ __launch_bounds__(256) void k_read(const u16* __restrict__ out_bf,
                                              const u16* __restrict__ v_bf,
                                              const u16* __restrict__ W_seg,
                                              u16* __restrict__ reads_bf,
                                              const float* __restrict__ decay,
                                              int c0, int nslots) {
  __shared__ u16 lds4[74752];
  u16* RK  = lds4;               // [64][520]  rk chunk, row-major [t][e]
  u16* RG2 = lds4 + 64*520;      // [256][72]  wk block / W block / epilogue
  u16* VT4 = RG2 + 256*72;       // [256][72]  v^T [d_local][s]
  u16* PS  = VT4 + 256*72;       // [64][72]   P [t][s]
  const int tid = threadIdx.x;
  const int lane = tid & 63, w = tid >> 6;
  const int g = lane >> 4, lr = lane & 15;
  const int dh = blockIdx.x, slot = blockIdx.y, b = blockIdx.z;
  const int c = c0 + slot;
  const int dbase = dh * 256;
  const float gamma = 1.f / (1.f + __builtin_expf(-decay[0]));
  const float l2g = __builtin_log2f(gamma);
  const size_t bT = (size_t)b * Tn;
  const size_t rowbase = bT + (size_t)c * Cn;
  const size_t wbase = (((size_t)b*nslots + slot)*Dn + dbase) * (size_t)Dn;

  // stage full rk chunk (straight copy)
#pragma unroll
  for (int i = 0; i < 32; ++i) {
    int sl = i*256 + tid;
    int t = sl >> 7, c4 = (sl & 127) << 2;
    *(us4_t*)&RK[t*520 + c4] = *(const us4_t*)&out_bf[(rowbase + t)*Dn + c4];
  }
  // stage v^T (transposed scalar writes)
#pragma unroll
  for (int i = 0; i < 16; ++i) {
    int sl = i*256 + tid;
    int s = sl >> 6, q4 = (sl & 63) << 2;
    us4_t vv = *(const us4_t*)&v_bf[(rowbase + s)*Dn + dbase + q4];
    VT4[(q4+0)*72 + s] = vv.x;
    VT4[(q4+1)*72 + s] = vv.y;
    VT4[(q4+2)*72 + s] = vv.z;
    VT4[(q4+3)*72 + s] = vv.w;
  }

  // phase 1: S^T[s][t] = sum_e wk[s][e] rk[t][e]; wave w owns s-range w*16..+15
  f4_t sacc[4];
#pragma unroll
  for (int i = 0; i < 4; ++i) sacc[i] = (f4_t){0.f, 0.f, 0.f, 0.f};
  for (int eb = 0; eb < 8; ++eb) {
    __syncthreads();
#pragma unroll
    for (int i = 0; i < 4; ++i) {
      int sl = i*256 + tid;
      int s = sl >> 4, e4 = (sl & 15) << 2;
      us4_t wv = {0, 0, 0, 0};
      int wr = c*Cn + s - 1;
      if (wr >= 0) wv = *(const us4_t*)&out_bf[(bT + wr)*Dn + eb*64 + e4];
      *(us4_t*)&RG2[s*72 + e4] = wv;
    }
    __syncthreads();
#pragma unroll
    for (int kk = 0; kk < 2; ++kk) {
      const int co = kk*32 + g*8;
      bf8_t a = *(const bf8_t*)&RG2[(w*16 + lr)*72 + co];
#pragma unroll
      for (int nf = 0; nf < 4; ++nf) {
        bf8_t bb = *(const bf8_t*)&RK[(nf*16 + lr)*520 + eb*64 + co];
        sacc[nf] = MFMA16(a, bb, sacc[nf]);
      }
    }
  }
  // phase 2: P[t][s] = S[t][s]*M[t][s] (bf16) -> PS
#pragma unroll
  for (int nf = 0; nf < 4; ++nf) {
    int t = nf*16 + lr;
#pragma unroll
    for (int r = 0; r < 4; ++r) {
      int s = w*16 + g*4 + r;
      float mval = (t > s) ? __builtin_exp2f(l2g * (float)(t - 1 - s)) : 0.f;
      PS[t*72 + s] = f2bf(sacc[nf][r] * mval);
    }
  }

  // phase 3: inter^T[d][t] = sum_e W[d][e] rk[t][e]; wave w owns d-range w*64..+63
  f4_t acc[4][4];
#pragma unroll
  for (int i = 0; i < 4; ++i)
#pragma unroll
    for (int j = 0; j < 4; ++j) acc[i][j] = (f4_t){0.f, 0.f, 0.f, 0.f};
  for (int eb = 0; eb < 8; ++eb) {
    __syncthreads();
#pragma unroll
    for (int i = 0; i < 16; ++i) {
      int sl = i*256 + tid;
      int d = sl >> 4, e4 = (sl & 15) << 2;
      *(us4_t*)&RG2[d*72 + e4] = *(const us4_t*)&W_seg[wbase + (size_t)d*Dn + eb*64 + e4];
    }
    __syncthreads();
#pragma unroll
    for (int kk = 0; kk < 2; ++kk) {
      const int co = kk*32 + g*8;
      bf8_t a[4], bb[4];
#pragma unroll
      for (int mf = 0; mf < 4; ++mf) a[mf] = *(const bf8_t*)&RG2[(w*64 + mf*16 + lr)*72 + co];
#pragma unroll
      for (int nf = 0; nf < 4; ++nf) bb[nf] = *(const bf8_t*)&RK[(nf*16 + lr)*520 + eb*64 + co];
#pragma unroll
      for (int mf = 0; mf < 4; ++mf)
#pragma unroll
        for (int nf = 0; nf < 4; ++nf)
          acc[mf][nf] = MFMA16(a[mf], bb[nf], acc[mf][nf]);
    }
  }
  // phase 4: scale inter by gamma^t (t = col)
#pragma unroll
  for (int nf = 0; nf < 4; ++nf) {
    float gp = __builtin_exp2f(l2g * (float)(nf*16 + lr));
#pragma unroll
    for (int mf = 0; mf < 4; ++mf) acc[mf][nf] = acc[mf][nf] * gp;
  }
  // phase 5: intra^T[d][t] += sum_s v^T[d][s] P[t][s]
#pragma unroll
  for (int kk = 0; kk < 2; ++kk) {
    const int co = kk*32 + g*8;
    bf8_t a[4], bb[4];
#pragma unroll
    for (int mf = 0; mf < 4; ++mf) a[mf] = *(const bf8_t*)&VT4[(w*64 + mf*16 + lr)*72 + co];
#pragma unroll
    for (int nf = 0; nf < 4; ++nf) bb[nf] = *(const bf8_t*)&PS[(nf*16 + lr)*72 + co];
#pragma unroll
    for (int mf = 0; mf < 4; ++mf)
#pragma unroll
      for (int nf = 0; nf < 4; ++nf)
        acc[mf][nf] = MFMA16(a[mf], bb[nf], acc[mf][nf]);
  }
  // phase 6: transpose epilogue -> reads_bf [t][d] coalesced
  __syncthreads();
  u16* EP = RG2;  // [64][264]
#pragma unroll
  for (int mf = 0; mf < 4; ++mf)
#pragma unroll
    for (int nf = 0; nf < 4; ++nf)
#pragma unroll
      for (int r = 0; r < 4; ++r)
        EP[(nf*16 + lr)*264 + w*64 + mf*16 + g*4 + r] = f2bf(acc[mf][nf][r]);
  __syncthreads();
#pragma unroll
  for (int i = 0; i < 8; ++i) {
    int sl = i*256 + tid;
    int t = sl >> 5, d8 = (sl & 31) << 3;
    *(us8_t*)&reads_bf[(rowbase + t)*Dn + dbase + d8] = *(const us8_t*)&EP[t*264 + d8];
  }
}

// ---------------- K5: out = resid + alpha * (reads @ w_read^T) ----------------
__global__ __launch_bounds__(256) void k_final(const u16* __restrict__ A,
                                               const u16* __restrict__ Bm,
                                               const float* __restrict__ resid,
                                               float* __restrict__ Cout) {
  __shared__ u16 lds[128*72*2];
  u16* As = lds;
  u16* Bs = lds + 128*72;
  const int tid = threadIdx.x;
  const int lane = tid & 63, w = tid >> 6;
  const int g = lane >> 4, lr = lane & 15;
  const int m0 = blockIdx.y * 128, n0 = blockIdx.x * 128;
  const int wm = (w >> 1) * 64, wn = (w & 1) * 64;
  f4_t acc[4][4];
#pragma unroll
  for (int i = 0; i < 4; ++i)
#pragma unroll
    for (int j = 0; j < 4; ++j) acc[i][j] = (f4_t){0.f, 0.f, 0.f, 0.f};

  for (int kb = 0; kb < 8; ++kb) {
    const int k0 = kb * 64;
    __syncthreads();
#pragma unroll
    for (int i = 0; i < 8; ++i) {
      int slot = i * 256 + tid;
      int r = slot >> 4, c4 = (slot & 15) << 2;
      *(us4_t*)&As[r*72 + c4] = *(const us4_t*)&A[(m0 + r)*Dn + k0 + c4];
      *(us4_t*)&Bs[r*72 + c4] = *(const us4_t*)&Bm[(n0 + r)*Dn + k0 + c4];
    }
    __syncthreads();
#pragma unroll
    for (int kk = 0; kk < 2; ++kk) {
      const int co = kk*32 + g*8;
      bf8_t a[4], b[4];
#pragma unroll
      for (int mf = 0; mf < 4; ++mf) a[mf] = *(const bf8_t*)&As[(wm + mf*16 + lr)*72 + co];
#pragma unroll
      for (int nf = 0; nf < 4; ++nf) b[nf] = *(const bf8_t*)&Bs[(wn + nf*16 + lr)*72 + co];
#pragma unroll
      for (int mf = 0; mf < 4; ++mf)
#pragma unroll
        for (int nf = 0; nf < 4; ++nf)
          acc[mf][nf] = MFMA16(a[mf], b[nf], acc[mf][nf]);
    }
  }
  // fused residual epilogue
#pragma unroll
  for (int mf = 0; mf < 4; ++mf)
#pragma unroll
    for (int nf = 0; nf < 4; ++nf)
#pragma unroll
      for (int r = 0; r < 4; ++r) {
        int row = m0 + wm + mf*16 + g*4 + r;
        int col = n0 + wn + nf*16 + lr;
        int idx = row * Dn + col;
        Cout[idx] = resid[idx] + ALPHAc * acc[mf][nf][r];
      }
}

extern "C" void kernel_launch(void* const* d_in, const int* in_sizes, int n_in,
                              void* d_out, int out_size, void* d_ws, size_t ws_size,
                              hipStream_t stream) {
  const float* out_f   = (const float*)d_in[0];
  const float* w_write = (const float*)d_in[1];
  const float* w_read  = (const float*)d_in[2];
  const float* decay   = (const float*)d_in[3];
  float* outp = (float*)d_out;

  char* ws = (char*)d_ws;
  // fixed layout: out_bf 32MB | v_bf 32MB | wwt .5MB | wrd .5MB | reads_bf 32MB | ckpt 4MB | W_seg rest
  u16*   out_bf   = (u16*)(ws);
  u16*   v_bf     = (u16*)(ws + (size_t)33554432);
  u16*   wwt_bf   = (u16*)(ws + (size_t)67108864);
  u16*   wrd_bf   = (u16*)(ws + (size_t)67633152);
  u16*   reads_bf = (u16*)(ws + (size_t)68157440);
  float* ckpt     = (float*)(ws + (size_t)101711872);
  u16*   W_seg    = (u16*)(ws + (size_t)105906176);

  // how many chunk-slots of W history fit in the remaining workspace?
  const size_t FIXED = 105906176ull;
  const size_t WPC = 2097152ull;  // bytes per chunk slot: 4b*512*512*2
  size_t avail = (ws_size > FIXED) ? (ws_size - FIXED) : 0;
  long maxslots = (long)(avail / WPC);
  if (maxslots < 1) maxslots = 1;
  if (maxslots > NCn) maxslots = NCn;
  int nseg = (NCn + (int)maxslots - 1) / (int)maxslots;
  int slots = (NCn + nseg - 1) / nseg;

  k_convert<<<16384, 256, 0, stream>>>(out_f, out_bf, 4194304);
  k_convert<<<256, 256, 0, stream>>>(w_write, wwt_bf, 65536);
  k_convert<<<256, 256, 0, stream>>>(w_read, wrd_bf, 65536);
  k_gemm_v<<<dim3(4, 256), 256, 0, stream>>>(out_bf, wwt_bf, v_bf);

  for (int s = 0; s < nseg; ++s) {
    int c0 = s * slots;
    if (c0 >= NCn) break;
    int nc = (c0 + slots <= NCn) ? slots : (NCn - c0);
    k_scan<<<dim3(8, 8, 4), 256, 0, stream>>>(out_bf, v_bf, W_seg, ckpt, decay,
                                              c0, nc, slots, s == 0 ? 1 : 0);
    k_read<<<dim3(2, nc, 4), 256, 0, stream>>>(out_bf, v_bf, W_seg, reads_bf, decay,
                                               c0, slots);
  }

  k_final<<<dim3(4, 256), 256, 0, stream>>>(reads_bf, wrd_bf, out_f, outp);
}